// Round 1
// baseline (1056.994 us; speedup 1.0000x reference)
//
#include <hip/hip_runtime.h>

typedef _Float16 half8 __attribute__((ext_vector_type(8)));
typedef _Float16 half4v __attribute__((ext_vector_type(4)));
typedef _Float16 half2v __attribute__((ext_vector_type(2)));
typedef float f32x4 __attribute__((ext_vector_type(4)));

// ---------------- fp32 -> fp16 conversion (with zero-padding past n4) -------
__global__ void cvt_f32_f16(const float* __restrict__ src, _Float16* __restrict__ dst,
                            int n4, int ntot4) {
    int i = blockIdx.x * blockDim.x + threadIdx.x;
    if (i >= ntot4) return;
    float4 v;
    if (i < n4) v = reinterpret_cast<const float4*>(src)[i];
    else        v = make_float4(0.f, 0.f, 0.f, 0.f);
    half4v h;
    h[0] = (_Float16)v.x; h[1] = (_Float16)v.y;
    h[2] = (_Float16)v.z; h[3] = (_Float16)v.w;
    reinterpret_cast<half4v*>(dst)[i] = h;
}

// ---------------- out[i][o] = bias[o] ---------------------------------------
__global__ void init_bias(float* __restrict__ out, const float* __restrict__ bias, int n4) {
    int i = blockIdx.x * blockDim.x + threadIdx.x;
    if (i >= n4) return;
    reinterpret_cast<float4*>(out)[i] = reinterpret_cast<const float4*>(bias)[i & 31];
}

// ---------------- GEMM: Y[m, kcell*128+o] = sum_c X[m,c] * W[kcell,o,c] -----
// Tile 128x128 per block, K=128 single shot, 16x16x32 f16 MFMA.
// LDS layout: halfword idx = row*128 + ((chunk ^ (row&15))*8 + k%8), chunk=k/8.
__global__ __launch_bounds__(256) void gemm_xw(
    const _Float16* __restrict__ Xh,   // [Mpad][128]
    const _Float16* __restrict__ Wh,   // [K][128][128]  (o-major, c contiguous)
    _Float16* __restrict__ Y,          // [Mpad][K*128]
    int ldY) {
    __shared__ ushort sA[128 * 128];
    __shared__ ushort sB[128 * 128];
    const int tid = threadIdx.x;
    const int m0 = blockIdx.x * 128;
    const int kcell = blockIdx.y;
    const ushort* Ag = (const ushort*)Xh + (size_t)m0 * 128;
    const ushort* Bg = (const ushort*)Wh + (size_t)kcell * 128 * 128;

#pragma unroll
    for (int it = 0; it < 8; ++it) {
        int p = it * 256 + tid;          // 16B-chunk index within the 32KB tile
        int row = p >> 4;
        int cpos = p & 15;
        int csrc = cpos ^ (row & 15);    // fetch the chunk that belongs at cpos
        int goff = row * 128 + csrc * 8; // halfwords
        int loff = row * 128 + cpos * 8;
        __builtin_amdgcn_global_load_lds(
            (const __attribute__((address_space(1))) void*)(Ag + goff),
            (__attribute__((address_space(3))) void*)(&sA[loff]), 16, 0, 0);
        __builtin_amdgcn_global_load_lds(
            (const __attribute__((address_space(1))) void*)(Bg + goff),
            (__attribute__((address_space(3))) void*)(&sB[loff]), 16, 0, 0);
    }
    __builtin_amdgcn_s_waitcnt(0);
    __syncthreads();

    const int lane = tid & 63;
    const int wid = tid >> 6;
    const int wm = wid & 1, wn = wid >> 1;   // 2x2 wave quadrants of 64x64
    const int mrow = lane & 15;
    const int g = lane >> 4;

    f32x4 acc[4][4] = {};
#pragma unroll
    for (int kb = 0; kb < 4; ++kb) {
        half8 af[4], bf[4];
#pragma unroll
        for (int t = 0; t < 4; ++t) {
            int cpos8 = ((kb * 4 + g) ^ mrow) * 8;
            int ra = wm * 64 + t * 16 + mrow;
            af[t] = *reinterpret_cast<const half8*>(&sA[ra * 128 + cpos8]);
            int rb = wn * 64 + t * 16 + mrow;
            bf[t] = *reinterpret_cast<const half8*>(&sB[rb * 128 + cpos8]);
        }
#pragma unroll
        for (int mt = 0; mt < 4; ++mt)
#pragma unroll
            for (int nt = 0; nt < 4; ++nt)
                acc[mt][nt] = __builtin_amdgcn_mfma_f32_16x16x32_f16(
                    af[mt], bf[nt], acc[mt][nt], 0, 0, 0);
    }

    // Epilogue: C/D layout col=lane&15, row=(lane>>4)*4+reg
    _Float16* Yt = Y + (size_t)m0 * ldY + kcell * 128;
#pragma unroll
    for (int mt = 0; mt < 4; ++mt) {
#pragma unroll
        for (int nt = 0; nt < 4; ++nt) {
            int col = wn * 64 + nt * 16 + mrow;
#pragma unroll
            for (int r = 0; r < 4; ++r) {
                int row = wm * 64 + mt * 16 + g * 4 + r;
                Yt[(size_t)row * ldY + col] = (_Float16)acc[mt][nt][r];
            }
        }
    }
}

// ---------------- scatter: out[i] += Y[j, k] --------------------------------
__global__ __launch_bounds__(256) void scatter_edges(
    const _Float16* __restrict__ Y, const int* __restrict__ ih,
    const int* __restrict__ jl, const int* __restrict__ kc,
    float* __restrict__ out, int E, int ldY) {
    int e = blockIdx.x * 4 + (threadIdx.x >> 6);
    if (e >= E) return;
    int lane = threadIdx.x & 63;
    int i = ih[e], j = jl[e], k = kc[e];
    half2v h = *reinterpret_cast<const half2v*>(Y + (size_t)j * ldY + k * 128 + lane * 2);
    float* dst = out + (size_t)i * 128 + lane * 2;
    unsafeAtomicAdd(dst + 0, (float)h[0]);
    unsafeAtomicAdd(dst + 1, (float)h[1]);
}

// ---------------- fallback (ws too small): direct per-edge matvec -----------
__global__ void fallback_edge(const float* __restrict__ x, const float* __restrict__ w,
                              const int* __restrict__ ih, const int* __restrict__ jl,
                              const int* __restrict__ kc, float* __restrict__ out, int E) {
    int e = blockIdx.x;
    if (e >= E) return;
    int lane = threadIdx.x;   // 64 threads
    int i = ih[e], j = jl[e], k = kc[e];
    const float* xr = x + (size_t)j * 128;
    const float* wk = w + (size_t)k * 128 * 128;
    float s0 = 0.f, s1 = 0.f;
    for (int c = 0; c < 128; ++c) {
        float xv = xr[c];
        s0 += wk[(size_t)lane * 128 + c] * xv;
        s1 += wk[(size_t)(lane + 64) * 128 + c] * xv;
    }
    unsafeAtomicAdd(&out[(size_t)i * 128 + lane], s0);
    unsafeAtomicAdd(&out[(size_t)i * 128 + 64 + lane], s1);
}

extern "C" void kernel_launch(void* const* d_in, const int* in_sizes, int n_in,
                              void* d_out, int out_size, void* d_ws, size_t ws_size,
                              hipStream_t stream) {
    const float* x    = (const float*)d_in[0];
    const float* w    = (const float*)d_in[1];
    const float* bias = (const float*)d_in[2];
    const int*   ih   = (const int*)d_in[3];
    const int*   jl   = (const int*)d_in[4];
    const int*   kc   = (const int*)d_in[5];
    float* out = (float*)d_out;

    const int C = 128;
    const int Nlow = in_sizes[0] / C;
    const int K = in_sizes[1] / (C * C);
    const int E = in_sizes[3];
    const int ldY = K * C;

    const int mtiles = (Nlow + 127) / 128;
    const int Mpad = mtiles * 128;

    size_t xh_bytes = (size_t)Mpad * C * 2;
    size_t wh_bytes = (size_t)K * C * C * 2;
    size_t y_off = (xh_bytes + wh_bytes + 255) & ~(size_t)255;
    size_t y_bytes = (size_t)Mpad * ldY * 2;
    size_t need = y_off + y_bytes;

    int n4out = out_size / 4;
    init_bias<<<(n4out + 255) / 256, 256, 0, stream>>>(out, bias, n4out);

    if (ws_size >= need) {
        _Float16* Xh = (_Float16*)d_ws;
        _Float16* Wh = (_Float16*)((char*)d_ws + xh_bytes);
        _Float16* Y  = (_Float16*)((char*)d_ws + y_off);
        int xv4 = Nlow * C / 4, xt4 = Mpad * C / 4;
        cvt_f32_f16<<<(xt4 + 255) / 256, 256, 0, stream>>>(x, Xh, xv4, xt4);
        int w4 = K * C * C / 4;
        cvt_f32_f16<<<(w4 + 255) / 256, 256, 0, stream>>>(w, Wh, w4, w4);
        gemm_xw<<<dim3(mtiles, K), 256, 0, stream>>>(Xh, Wh, Y, ldY);
        scatter_edges<<<(E + 3) / 4, 256, 0, stream>>>(Y, ih, jl, kc, out, E, ldY);
    } else {
        fallback_edge<<<E, 64, 0, stream>>>(x, w, ih, jl, kc, out, E);
    }
}

// Round 2
// 484.267 us; speedup vs baseline: 2.1827x; 2.1827x over previous
//
#include <hip/hip_runtime.h>

typedef _Float16 half8 __attribute__((ext_vector_type(8)));
typedef _Float16 half4v __attribute__((ext_vector_type(4)));
typedef _Float16 half2v __attribute__((ext_vector_type(2)));
typedef float f32x4 __attribute__((ext_vector_type(4)));

#define CAP 32          // bucket capacity per output point (mean load = 5)
#define OVF_MAX 4096

// ---------------- fp32 -> fp16 conversion (with zero-padding past n4) -------
__global__ void cvt_f32_f16(const float* __restrict__ src, _Float16* __restrict__ dst,
                            int n4, int ntot4) {
    int i = blockIdx.x * blockDim.x + threadIdx.x;
    if (i >= ntot4) return;
    float4 v;
    if (i < n4) v = reinterpret_cast<const float4*>(src)[i];
    else        v = make_float4(0.f, 0.f, 0.f, 0.f);
    half4v h;
    h[0] = (_Float16)v.x; h[1] = (_Float16)v.y;
    h[2] = (_Float16)v.z; h[3] = (_Float16)v.w;
    reinterpret_cast<half4v*>(dst)[i] = h;
}

// ---------------- zero the per-point counters (+ overflow counter) ----------
__global__ void zero_ints(int* __restrict__ p, int n) {
    int i = blockIdx.x * blockDim.x + threadIdx.x;
    if (i < n) p[i] = 0;
}

// ---------------- out[i][o] = bias[o] (atomic-fallback path only) -----------
__global__ void init_bias(float* __restrict__ out, const float* __restrict__ bias, int n4) {
    int i = blockIdx.x * blockDim.x + threadIdx.x;
    if (i >= n4) return;
    reinterpret_cast<float4*>(out)[i] = reinterpret_cast<const float4*>(bias)[i & 31];
}

// ---------------- GEMM: Y[m, kcell*128+o] = sum_c X[m,c] * W[kcell,o,c] -----
__global__ __launch_bounds__(256) void gemm_xw(
    const _Float16* __restrict__ Xh,   // [Mpad][128]
    const _Float16* __restrict__ Wh,   // [K][128][128]  (o-major, c contiguous)
    _Float16* __restrict__ Y,          // [Mpad][K*128]
    int ldY) {
    __shared__ ushort sA[128 * 128];
    __shared__ ushort sB[128 * 128];
    const int tid = threadIdx.x;
    const int m0 = blockIdx.x * 128;
    const int kcell = blockIdx.y;
    const ushort* Ag = (const ushort*)Xh + (size_t)m0 * 128;
    const ushort* Bg = (const ushort*)Wh + (size_t)kcell * 128 * 128;

#pragma unroll
    for (int it = 0; it < 8; ++it) {
        int p = it * 256 + tid;          // 16B-chunk index within the 32KB tile
        int row = p >> 4;
        int cpos = p & 15;
        int csrc = cpos ^ (row & 15);    // XOR swizzle keeps ds_read_b128 conflict-free
        int goff = row * 128 + csrc * 8; // halfwords
        int loff = row * 128 + cpos * 8;
        __builtin_amdgcn_global_load_lds(
            (const __attribute__((address_space(1))) void*)(Ag + goff),
            (__attribute__((address_space(3))) void*)(&sA[loff]), 16, 0, 0);
        __builtin_amdgcn_global_load_lds(
            (const __attribute__((address_space(1))) void*)(Bg + goff),
            (__attribute__((address_space(3))) void*)(&sB[loff]), 16, 0, 0);
    }
    __builtin_amdgcn_s_waitcnt(0);
    __syncthreads();

    const int lane = tid & 63;
    const int wid = tid >> 6;
    const int wm = wid & 1, wn = wid >> 1;   // 2x2 wave quadrants of 64x64
    const int mrow = lane & 15;
    const int g = lane >> 4;

    f32x4 acc[4][4] = {};
#pragma unroll
    for (int kb = 0; kb < 4; ++kb) {
        half8 af[4], bf[4];
#pragma unroll
        for (int t = 0; t < 4; ++t) {
            int cpos8 = ((kb * 4 + g) ^ mrow) * 8;
            int ra = wm * 64 + t * 16 + mrow;
            af[t] = *reinterpret_cast<const half8*>(&sA[ra * 128 + cpos8]);
            int rb = wn * 64 + t * 16 + mrow;
            bf[t] = *reinterpret_cast<const half8*>(&sB[rb * 128 + cpos8]);
        }
#pragma unroll
        for (int mt = 0; mt < 4; ++mt)
#pragma unroll
            for (int nt = 0; nt < 4; ++nt)
                acc[mt][nt] = __builtin_amdgcn_mfma_f32_16x16x32_f16(
                    af[mt], bf[nt], acc[mt][nt], 0, 0, 0);
    }

    // Epilogue: C/D layout col=lane&15, row=(lane>>4)*4+reg
    _Float16* Yt = Y + (size_t)m0 * ldY + kcell * 128;
#pragma unroll
    for (int mt = 0; mt < 4; ++mt) {
#pragma unroll
        for (int nt = 0; nt < 4; ++nt) {
            int col = wn * 64 + nt * 16 + mrow;
#pragma unroll
            for (int r = 0; r < 4; ++r) {
                int row = wm * 64 + mt * 16 + g * 4 + r;
                Yt[(size_t)row * ldY + col] = (_Float16)acc[mt][nt][r];
            }
        }
    }
}

// ---------------- bucket fill: counts[i]++, bucket[i][pos] = Y-offset -------
__global__ __launch_bounds__(256) void fill_buckets(
    const int* __restrict__ ih, const int* __restrict__ jl, const int* __restrict__ kc,
    int* __restrict__ counts, int* __restrict__ bucket,
    int* __restrict__ ovf_cnt, int* __restrict__ ovf_list,
    int E, int ldY) {
    int e = blockIdx.x * blockDim.x + threadIdx.x;
    if (e >= E) return;
    int i = ih[e];
    int off = jl[e] * ldY + kc[e] * 128;   // halfword offset into Y
    int pos = atomicAdd(&counts[i], 1);
    if (pos < CAP) {
        bucket[(size_t)i * CAP + pos] = off;
    } else {
        int o = atomicAdd(ovf_cnt, 1);
        if (o < OVF_MAX) { ovf_list[2 * o] = i; ovf_list[2 * o + 1] = off; }
    }
}

// ---------------- gather: out[i] = bias + sum_{e in bucket[i]} Y[off_e] -----
__global__ __launch_bounds__(256) void gather_out(
    const _Float16* __restrict__ Y, const int* __restrict__ counts,
    const int* __restrict__ bucket, const float* __restrict__ bias,
    float* __restrict__ out, int Nhigh) {
    int i = blockIdx.x * 4 + (threadIdx.x >> 6);
    if (i >= Nhigh) return;
    int lane = threadIdx.x & 63;
    int nb = counts[i];
    if (nb > CAP) nb = CAP;
    const int* bk = bucket + (size_t)i * CAP;
    int offs = bk[lane & 31];               // whole bucket row in-register
    float2 acc;
    acc.x = bias[lane * 2];
    acc.y = bias[lane * 2 + 1];
    for (int e = 0; e < nb; ++e) {
        int off = __shfl(offs, e);
        half2v h = *reinterpret_cast<const half2v*>(Y + (size_t)off + lane * 2);
        acc.x += (float)h[0];
        acc.y += (float)h[1];
    }
    *reinterpret_cast<float2*>(out + (size_t)i * 128 + lane * 2) = acc;
}

// ---------------- rare overflow application (normally 0 entries) ------------
__global__ void apply_overflow(const int* __restrict__ ovf_cnt, const int* __restrict__ ovf_list,
                               const _Float16* __restrict__ Y, float* __restrict__ out) {
    int n = *ovf_cnt;
    if (n > OVF_MAX) n = OVF_MAX;
    int lane = threadIdx.x & 63;
    int w = threadIdx.x >> 6;        // 4 waves, 1 block
    for (int o = w; o < n; o += 4) {
        int i = ovf_list[2 * o], off = ovf_list[2 * o + 1];
        half2v h = *reinterpret_cast<const half2v*>(Y + (size_t)off + lane * 2);
        float* dst = out + (size_t)i * 128 + lane * 2;
        unsafeAtomicAdd(dst + 0, (float)h[0]);
        unsafeAtomicAdd(dst + 1, (float)h[1]);
    }
}

// ---------------- tier-2: per-edge atomic scatter ---------------------------
__global__ __launch_bounds__(256) void scatter_edges(
    const _Float16* __restrict__ Y, const int* __restrict__ ih,
    const int* __restrict__ jl, const int* __restrict__ kc,
    float* __restrict__ out, int E, int ldY) {
    int e = blockIdx.x * 4 + (threadIdx.x >> 6);
    if (e >= E) return;
    int lane = threadIdx.x & 63;
    int i = ih[e], j = jl[e], k = kc[e];
    half2v h = *reinterpret_cast<const half2v*>(Y + (size_t)j * ldY + k * 128 + lane * 2);
    float* dst = out + (size_t)i * 128 + lane * 2;
    unsafeAtomicAdd(dst + 0, (float)h[0]);
    unsafeAtomicAdd(dst + 1, (float)h[1]);
}

// ---------------- tier-3 fallback: direct per-edge matvec -------------------
__global__ void fallback_edge(const float* __restrict__ x, const float* __restrict__ w,
                              const int* __restrict__ ih, const int* __restrict__ jl,
                              const int* __restrict__ kc, float* __restrict__ out, int E) {
    int e = blockIdx.x;
    if (e >= E) return;
    int lane = threadIdx.x;   // 64 threads
    int i = ih[e], j = jl[e], k = kc[e];
    const float* xr = x + (size_t)j * 128;
    const float* wk = w + (size_t)k * 128 * 128;
    float s0 = 0.f, s1 = 0.f;
    for (int c = 0; c < 128; ++c) {
        float xv = xr[c];
        s0 += wk[(size_t)lane * 128 + c] * xv;
        s1 += wk[(size_t)(lane + 64) * 128 + c] * xv;
    }
    unsafeAtomicAdd(&out[(size_t)i * 128 + lane], s0);
    unsafeAtomicAdd(&out[(size_t)i * 128 + 64 + lane], s1);
}

extern "C" void kernel_launch(void* const* d_in, const int* in_sizes, int n_in,
                              void* d_out, int out_size, void* d_ws, size_t ws_size,
                              hipStream_t stream) {
    const float* x    = (const float*)d_in[0];
    const float* w    = (const float*)d_in[1];
    const float* bias = (const float*)d_in[2];
    const int*   ih   = (const int*)d_in[3];
    const int*   jl   = (const int*)d_in[4];
    const int*   kc   = (const int*)d_in[5];
    float* out = (float*)d_out;

    const int C = 128;
    const int Nlow = in_sizes[0] / C;
    const int K = in_sizes[1] / (C * C);
    const int E = in_sizes[3];
    const int ldY = K * C;
    const int Nhigh = out_size / C;

    const int mtiles = (Nlow + 127) / 128;
    const int Mpad = mtiles * 128;

    // ---- workspace layout -------------------------------------------------
    size_t off = 0;
    auto alloc = [&](size_t bytes) { size_t o = off; off = (off + bytes + 255) & ~(size_t)255; return o; };
    size_t xh_off   = alloc((size_t)Mpad * C * 2);
    size_t wh_off   = alloc((size_t)K * C * C * 2);
    size_t cnt_off  = alloc(((size_t)Nhigh + 1) * 4);        // counts + ovf counter
    size_t ovl_off  = alloc((size_t)OVF_MAX * 2 * 4);
    size_t bkt_off  = alloc((size_t)Nhigh * CAP * 4);
    size_t y_off    = alloc((size_t)Mpad * ldY * 2);
    size_t need_sort = off;
    size_t need_gemm = y_off;  // everything before Y is reusable; atomic tier needs Xh..Y

    _Float16* Xh = (_Float16*)((char*)d_ws + xh_off);
    _Float16* Wh = (_Float16*)((char*)d_ws + wh_off);
    int* counts  = (int*)((char*)d_ws + cnt_off);
    int* ovf_cnt = counts + Nhigh;
    int* ovf_lst = (int*)((char*)d_ws + ovl_off);
    int* bucket  = (int*)((char*)d_ws + bkt_off);
    _Float16* Y  = (_Float16*)((char*)d_ws + y_off);

    if (ws_size >= need_sort) {
        int xv4 = Nlow * C / 4, xt4 = Mpad * C / 4;
        cvt_f32_f16<<<(xt4 + 255) / 256, 256, 0, stream>>>(x, Xh, xv4, xt4);
        int w4 = K * C * C / 4;
        cvt_f32_f16<<<(w4 + 255) / 256, 256, 0, stream>>>(w, Wh, w4, w4);
        zero_ints<<<(Nhigh + 1 + 255) / 256, 256, 0, stream>>>(counts, Nhigh + 1);
        gemm_xw<<<dim3(mtiles, K), 256, 0, stream>>>(Xh, Wh, Y, ldY);
        fill_buckets<<<(E + 255) / 256, 256, 0, stream>>>(
            ih, jl, kc, counts, bucket, ovf_cnt, ovf_lst, E, ldY);
        gather_out<<<(Nhigh + 3) / 4, 256, 0, stream>>>(Y, counts, bucket, bias, out, Nhigh);
        apply_overflow<<<1, 256, 0, stream>>>(ovf_cnt, ovf_lst, Y, out);
    } else if (ws_size >= need_gemm + (size_t)Mpad * ldY * 2) {
        int n4out = out_size / 4;
        init_bias<<<(n4out + 255) / 256, 256, 0, stream>>>(out, bias, n4out);
        int xv4 = Nlow * C / 4, xt4 = Mpad * C / 4;
        cvt_f32_f16<<<(xt4 + 255) / 256, 256, 0, stream>>>(x, Xh, xv4, xt4);
        int w4 = K * C * C / 4;
        cvt_f32_f16<<<(w4 + 255) / 256, 256, 0, stream>>>(w, Wh, w4, w4);
        gemm_xw<<<dim3(mtiles, K), 256, 0, stream>>>(Xh, Wh, Y, ldY);
        scatter_edges<<<(E + 3) / 4, 256, 0, stream>>>(Y, ih, jl, kc, out, E, ldY);
    } else {
        int n4out = out_size / 4;
        init_bias<<<(n4out + 255) / 256, 256, 0, stream>>>(out, bias, n4out);
        fallback_edge<<<E, 64, 0, stream>>>(x, w, ih, jl, kc, out, E);
    }
}

// Round 3
// 416.935 us; speedup vs baseline: 2.5352x; 1.1615x over previous
//
#include <hip/hip_runtime.h>

typedef _Float16 half8 __attribute__((ext_vector_type(8)));
typedef _Float16 half4v __attribute__((ext_vector_type(4)));
typedef _Float16 half2v __attribute__((ext_vector_type(2)));
typedef float f32x4 __attribute__((ext_vector_type(4)));

#define CAP 32          // bucket capacity per output point (mean load = 5)
#define OVF_MAX 4096

// ---------------- fp32 -> fp16 conversion of X (padded) and W, one launch ---
__global__ void cvt_inputs(const float* __restrict__ x, const float* __restrict__ w,
                           _Float16* __restrict__ Xh, _Float16* __restrict__ Wh,
                           int xv4, int xt4, int w4) {
    int i = blockIdx.x * blockDim.x + threadIdx.x;
    if (i < xt4) {
        float4 v = (i < xv4) ? reinterpret_cast<const float4*>(x)[i]
                             : make_float4(0.f, 0.f, 0.f, 0.f);
        half4v h; h[0]=(_Float16)v.x; h[1]=(_Float16)v.y; h[2]=(_Float16)v.z; h[3]=(_Float16)v.w;
        reinterpret_cast<half4v*>(Xh)[i] = h;
    } else {
        int j = i - xt4;
        if (j < w4) {
            float4 v = reinterpret_cast<const float4*>(w)[j];
            half4v h; h[0]=(_Float16)v.x; h[1]=(_Float16)v.y; h[2]=(_Float16)v.z; h[3]=(_Float16)v.w;
            reinterpret_cast<half4v*>(Wh)[j] = h;
        }
    }
}

// ---------------- zero the per-point counters (+ overflow counter) ----------
__global__ void zero_ints(int* __restrict__ p, int n) {
    int i = blockIdx.x * blockDim.x + threadIdx.x;
    if (i < n) p[i] = 0;
}

// ---------------- out[i][o] = bias[o] (atomic-fallback paths only) ----------
__global__ void init_bias(float* __restrict__ out, const float* __restrict__ bias, int n4) {
    int i = blockIdx.x * blockDim.x + threadIdx.x;
    if (i >= n4) return;
    reinterpret_cast<float4*>(out)[i] = reinterpret_cast<const float4*>(bias)[i & 31];
}

// ---------------- GEMM: Y[m, kcell*128+o] = sum_c X[m,c] * W[kcell,o,c] -----
// A-tile staged once per block; 3 kernel cells per block; next-B staging
// overlaps previous epilogue's global stores.
__global__ __launch_bounds__(256) void gemm_xw(
    const _Float16* __restrict__ Xh,   // [Mpad][128]
    const _Float16* __restrict__ Wh,   // [K][128][128]  (o-major, c contiguous)
    _Float16* __restrict__ Y,          // [Mpad][K*128]
    int ldY) {
    __shared__ ushort sA[128 * 128];
    __shared__ ushort sB[128 * 128];
    const int tid = threadIdx.x;
    const int m0 = blockIdx.x * 128;
    const int kc0 = blockIdx.y * 3;
    const ushort* Ag = (const ushort*)Xh + (size_t)m0 * 128;

#pragma unroll
    for (int it = 0; it < 8; ++it) {
        int p = it * 256 + tid;
        int row = p >> 4, cpos = p & 15;
        int csrc = cpos ^ (row & 15);   // XOR swizzle keeps ds_read_b128 conflict-free
        __builtin_amdgcn_global_load_lds(
            (const __attribute__((address_space(1))) void*)(Ag + row * 128 + csrc * 8),
            (__attribute__((address_space(3))) void*)(&sA[row * 128 + cpos * 8]), 16, 0, 0);
    }
    {   // stage B for kcell kc0
        const ushort* Bg = (const ushort*)Wh + (size_t)kc0 * 128 * 128;
#pragma unroll
        for (int it = 0; it < 8; ++it) {
            int p = it * 256 + tid;
            int row = p >> 4, cpos = p & 15;
            int csrc = cpos ^ (row & 15);
            __builtin_amdgcn_global_load_lds(
                (const __attribute__((address_space(1))) void*)(Bg + row * 128 + csrc * 8),
                (__attribute__((address_space(3))) void*)(&sB[row * 128 + cpos * 8]), 16, 0, 0);
        }
    }
    __builtin_amdgcn_s_waitcnt(0);
    __syncthreads();

    const int lane = tid & 63;
    const int wid = tid >> 6;
    const int wm = wid & 1, wn = wid >> 1;   // 2x2 wave quadrants of 64x64
    const int mrow = lane & 15;
    const int g = lane >> 4;

    for (int kk = 0; kk < 3; ++kk) {
        f32x4 acc[4][4] = {};
#pragma unroll
        for (int kb = 0; kb < 4; ++kb) {
            half8 af[4], bf[4];
#pragma unroll
            for (int t = 0; t < 4; ++t) {
                int cpos8 = ((kb * 4 + g) ^ mrow) * 8;
                int ra = wm * 64 + t * 16 + mrow;
                af[t] = *reinterpret_cast<const half8*>(&sA[ra * 128 + cpos8]);
                int rb = wn * 64 + t * 16 + mrow;
                bf[t] = *reinterpret_cast<const half8*>(&sB[rb * 128 + cpos8]);
            }
#pragma unroll
            for (int mt = 0; mt < 4; ++mt)
#pragma unroll
                for (int nt = 0; nt < 4; ++nt)
                    acc[mt][nt] = __builtin_amdgcn_mfma_f32_16x16x32_f16(
                        af[mt], bf[nt], acc[mt][nt], 0, 0, 0);
        }
        __syncthreads();                 // all waves done reading sB
        if (kk < 2) {                    // stage next B, overlapped with epilogue
            const ushort* Bg = (const ushort*)Wh + (size_t)(kc0 + kk + 1) * 128 * 128;
#pragma unroll
            for (int it = 0; it < 8; ++it) {
                int p = it * 256 + tid;
                int row = p >> 4, cpos = p & 15;
                int csrc = cpos ^ (row & 15);
                __builtin_amdgcn_global_load_lds(
                    (const __attribute__((address_space(1))) void*)(Bg + row * 128 + csrc * 8),
                    (__attribute__((address_space(3))) void*)(&sB[row * 128 + cpos * 8]), 16, 0, 0);
            }
        }
        // Epilogue (C/D layout col=lane&15, row=(lane>>4)*4+reg)
        _Float16* Yt = Y + (size_t)m0 * ldY + (kc0 + kk) * 128;
#pragma unroll
        for (int mt = 0; mt < 4; ++mt) {
#pragma unroll
            for (int nt = 0; nt < 4; ++nt) {
                int col = wn * 64 + nt * 16 + mrow;
#pragma unroll
                for (int r = 0; r < 4; ++r) {
                    int row = wm * 64 + mt * 16 + g * 4 + r;
                    Yt[(size_t)row * ldY + col] = (_Float16)acc[mt][nt][r];
                }
            }
        }
        if (kk < 2) {
            __builtin_amdgcn_s_waitcnt(0);
            __syncthreads();
        }
    }
}

// ---------------- bucket fill: counts[i]++, bucket[i][pos] = Y-offset -------
__global__ __launch_bounds__(256) void fill_buckets(
    const int* __restrict__ ih, const int* __restrict__ jl, const int* __restrict__ kc,
    int* __restrict__ counts, int* __restrict__ bucket,
    int* __restrict__ ovf_cnt, int* __restrict__ ovf_list,
    int E, int ldY) {
    int e = blockIdx.x * blockDim.x + threadIdx.x;
    if (e >= E) return;
    int i = ih[e];
    int off = jl[e] * ldY + kc[e] * 128;   // halfword offset into Y
    int pos = atomicAdd(&counts[i], 1);
    if (pos < CAP) {
        bucket[(size_t)i * CAP + pos] = off;
    } else {
        int o = atomicAdd(ovf_cnt, 1);
        if (o < OVF_MAX) { ovf_list[2 * o] = i; ovf_list[2 * o + 1] = off; }
    }
}

// ---------------- gather: out[i] = bias + sum_{e in bucket[i]} Y[off_e] -----
// Unroll-4: 4 independent row-loads in flight per wave (latency hiding).
__global__ __launch_bounds__(256) void gather_out(
    const _Float16* __restrict__ Y, const int* __restrict__ counts,
    const int* __restrict__ bucket, const float* __restrict__ bias,
    float* __restrict__ out, int Nhigh) {
    int i = blockIdx.x * 4 + (threadIdx.x >> 6);
    if (i >= Nhigh) return;
    int lane = threadIdx.x & 63;
    int nb = counts[i];
    if (nb > CAP) nb = CAP;
    const int* bk = bucket + (size_t)i * CAP;
    int offs = bk[lane & 31];               // whole bucket row held across lanes
    float2 acc;
    acc.x = bias[lane * 2];
    acc.y = bias[lane * 2 + 1];
    for (int e0 = 0; e0 < nb; e0 += 4) {
        float vx[4], vy[4];
#pragma unroll
        for (int u = 0; u < 4; ++u) {
            int e = e0 + u;
            bool valid = e < nb;
            int off = __shfl(offs, e & 31);
            off = valid ? off : 0;
            half2v h = *reinterpret_cast<const half2v*>(Y + (size_t)off + lane * 2);
            vx[u] = valid ? (float)h[0] : 0.f;
            vy[u] = valid ? (float)h[1] : 0.f;
        }
        acc.x += (vx[0] + vx[1]) + (vx[2] + vx[3]);
        acc.y += (vy[0] + vy[1]) + (vy[2] + vy[3]);
    }
    *reinterpret_cast<float2*>(out + (size_t)i * 128 + lane * 2) = acc;
}

// ---------------- rare overflow application (normally 0 entries) ------------
__global__ void apply_overflow(const int* __restrict__ ovf_cnt, const int* __restrict__ ovf_list,
                               const _Float16* __restrict__ Y, float* __restrict__ out) {
    int n = *ovf_cnt;
    if (n > OVF_MAX) n = OVF_MAX;
    int lane = threadIdx.x & 63;
    int w = threadIdx.x >> 6;        // 4 waves, 1 block
    for (int o = w; o < n; o += 4) {
        int i = ovf_list[2 * o], off = ovf_list[2 * o + 1];
        half2v h = *reinterpret_cast<const half2v*>(Y + (size_t)off + lane * 2);
        float* dst = out + (size_t)i * 128 + lane * 2;
        unsafeAtomicAdd(dst + 0, (float)h[0]);
        unsafeAtomicAdd(dst + 1, (float)h[1]);
    }
}

// ---------------- tier-3 fallback: direct per-edge matvec -------------------
__global__ void fallback_edge(const float* __restrict__ x, const float* __restrict__ w,
                              const int* __restrict__ ih, const int* __restrict__ jl,
                              const int* __restrict__ kc, float* __restrict__ out, int E) {
    int e = blockIdx.x;
    if (e >= E) return;
    int lane = threadIdx.x;   // 64 threads
    int i = ih[e], j = jl[e], k = kc[e];
    const float* xr = x + (size_t)j * 128;
    const float* wk = w + (size_t)k * 128 * 128;
    float s0 = 0.f, s1 = 0.f;
    for (int c = 0; c < 128; ++c) {
        float xv = xr[c];
        s0 += wk[(size_t)lane * 128 + c] * xv;
        s1 += wk[(size_t)(lane + 64) * 128 + c] * xv;
    }
    unsafeAtomicAdd(&out[(size_t)i * 128 + lane], s0);
    unsafeAtomicAdd(&out[(size_t)i * 128 + 64 + lane], s1);
}

extern "C" void kernel_launch(void* const* d_in, const int* in_sizes, int n_in,
                              void* d_out, int out_size, void* d_ws, size_t ws_size,
                              hipStream_t stream) {
    const float* x    = (const float*)d_in[0];
    const float* w    = (const float*)d_in[1];
    const float* bias = (const float*)d_in[2];
    const int*   ih   = (const int*)d_in[3];
    const int*   jl   = (const int*)d_in[4];
    const int*   kc   = (const int*)d_in[5];
    float* out = (float*)d_out;

    const int C = 128;
    const int Nlow = in_sizes[0] / C;
    const int K = in_sizes[1] / (C * C);
    const int E = in_sizes[3];
    const int ldY = K * C;
    const int Nhigh = out_size / C;

    const int mtiles = (Nlow + 127) / 128;
    const int Mpad = mtiles * 128;

    // ---- workspace layout -------------------------------------------------
    size_t off = 0;
    auto alloc = [&](size_t bytes) { size_t o = off; off = (off + bytes + 255) & ~(size_t)255; return o; };
    size_t xh_off   = alloc((size_t)Mpad * C * 2);
    size_t wh_off   = alloc((size_t)K * C * C * 2);
    size_t cnt_off  = alloc(((size_t)Nhigh + 1) * 4);        // counts + ovf counter
    size_t ovl_off  = alloc((size_t)OVF_MAX * 2 * 4);
    size_t bkt_off  = alloc((size_t)Nhigh * CAP * 4);
    size_t y_off    = alloc((size_t)Mpad * ldY * 2);
    size_t need_sort = off;

    _Float16* Xh = (_Float16*)((char*)d_ws + xh_off);
    _Float16* Wh = (_Float16*)((char*)d_ws + wh_off);
    int* counts  = (int*)((char*)d_ws + cnt_off);
    int* ovf_cnt = counts + Nhigh;
    int* ovf_lst = (int*)((char*)d_ws + ovl_off);
    int* bucket  = (int*)((char*)d_ws + bkt_off);
    _Float16* Y  = (_Float16*)((char*)d_ws + y_off);

    if (ws_size >= need_sort && (K % 3) == 0) {
        int xv4 = Nlow * C / 4, xt4 = Mpad * C / 4;
        int w4 = K * C * C / 4;
        cvt_inputs<<<(xt4 + w4 + 255) / 256, 256, 0, stream>>>(x, w, Xh, Wh, xv4, xt4, w4);
        zero_ints<<<(Nhigh + 1 + 255) / 256, 256, 0, stream>>>(counts, Nhigh + 1);
        gemm_xw<<<dim3(mtiles, K / 3), 256, 0, stream>>>(Xh, Wh, Y, ldY);
        fill_buckets<<<(E + 255) / 256, 256, 0, stream>>>(
            ih, jl, kc, counts, bucket, ovf_cnt, ovf_lst, E, ldY);
        gather_out<<<(Nhigh + 3) / 4, 256, 0, stream>>>(Y, counts, bucket, bias, out, Nhigh);
        apply_overflow<<<1, 256, 0, stream>>>(ovf_cnt, ovf_lst, Y, out);
    } else {
        int n4out = out_size / 4;
        init_bias<<<(n4out + 255) / 256, 256, 0, stream>>>(out, bias, n4out);
        fallback_edge<<<E, 64, 0, stream>>>(x, w, ih, jl, kc, out, E);
    }
}

// Round 4
// 397.671 us; speedup vs baseline: 2.6580x; 1.0484x over previous
//
#include <hip/hip_runtime.h>

typedef _Float16 half8 __attribute__((ext_vector_type(8)));
typedef _Float16 half4v __attribute__((ext_vector_type(4)));
typedef _Float16 half2v __attribute__((ext_vector_type(2)));
typedef float f32x4 __attribute__((ext_vector_type(4)));

#define CAP 32          // bucket capacity per output point (mean load = 5)
#define OVF_MAX 4096

// Y row-block internal permutation: position o' holds output channel
//   o = (o'>>6)*64 + (o'&3)*16 + ((o'>>2)&15)
// chosen so the GEMM epilogue can write 8B-contiguous pieces per lane.

// ---------------- fp32 -> fp16 conversion of X (padded), W, bias-perm -------
__global__ void cvt_inputs(const float* __restrict__ x, const float* __restrict__ w,
                           const float* __restrict__ bias,
                           _Float16* __restrict__ Xh, _Float16* __restrict__ Wh,
                           float* __restrict__ biasPerm,
                           int xv4, int xt4, int w4) {
    int i = blockIdx.x * blockDim.x + threadIdx.x;
    if (i < xt4) {
        float4 v = (i < xv4) ? reinterpret_cast<const float4*>(x)[i]
                             : make_float4(0.f, 0.f, 0.f, 0.f);
        half4v h; h[0]=(_Float16)v.x; h[1]=(_Float16)v.y; h[2]=(_Float16)v.z; h[3]=(_Float16)v.w;
        reinterpret_cast<half4v*>(Xh)[i] = h;
    } else if (i < xt4 + w4) {
        int j = i - xt4;
        float4 v = reinterpret_cast<const float4*>(w)[j];
        half4v h; h[0]=(_Float16)v.x; h[1]=(_Float16)v.y; h[2]=(_Float16)v.z; h[3]=(_Float16)v.w;
        reinterpret_cast<half4v*>(Wh)[j] = h;
    } else if (i < xt4 + w4 + 32) {
        int j2 = i - xt4 - w4;           // float4 index into biasPerm (o'=4*j2)
        int wn = j2 >> 4, mrow = j2 & 15;
        float4 v;
        v.x = bias[wn * 64 + 0 * 16 + mrow];
        v.y = bias[wn * 64 + 1 * 16 + mrow];
        v.z = bias[wn * 64 + 2 * 16 + mrow];
        v.w = bias[wn * 64 + 3 * 16 + mrow];
        reinterpret_cast<float4*>(biasPerm)[j2] = v;
    }
}

// ---------------- zero ints (counters / Y zero-row) -------------------------
__global__ void zero_ints(int* __restrict__ p, int n) {
    int i = blockIdx.x * blockDim.x + threadIdx.x;
    if (i < n) p[i] = 0;
}

// ---------------- out[i][o] = bias[o] (fallback path only) ------------------
__global__ void init_bias(float* __restrict__ out, const float* __restrict__ bias, int n4) {
    int i = blockIdx.x * blockDim.x + threadIdx.x;
    if (i >= n4) return;
    reinterpret_cast<float4*>(out)[i] = reinterpret_cast<const float4*>(bias)[i & 31];
}

// ---------------- GEMM: Y[m, kcell-block] = X[m,:] * W[kcell]^T -------------
// A-tile staged once per block; 3 kernel cells per block; vectorized epilogue
// writes 8B half4 pieces in the permuted row layout.
__global__ __launch_bounds__(256) void gemm_xw(
    const _Float16* __restrict__ Xh,   // [Mpad][128]
    const _Float16* __restrict__ Wh,   // [K][128][128]  (o-major, c contiguous)
    _Float16* __restrict__ Y,          // [Mpad][K*128]  (permuted row-blocks)
    int ldY) {
    __shared__ ushort sA[128 * 128];
    __shared__ ushort sB[128 * 128];
    const int tid = threadIdx.x;
    const int m0 = blockIdx.x * 128;
    const int kc0 = blockIdx.y * 3;
    const ushort* Ag = (const ushort*)Xh + (size_t)m0 * 128;

#pragma unroll
    for (int it = 0; it < 8; ++it) {
        int p = it * 256 + tid;
        int row = p >> 4, cpos = p & 15;
        int csrc = cpos ^ (row & 15);   // XOR swizzle keeps ds_read_b128 conflict-free
        __builtin_amdgcn_global_load_lds(
            (const __attribute__((address_space(1))) void*)(Ag + row * 128 + csrc * 8),
            (__attribute__((address_space(3))) void*)(&sA[row * 128 + cpos * 8]), 16, 0, 0);
    }
    {   // stage B for kcell kc0
        const ushort* Bg = (const ushort*)Wh + (size_t)kc0 * 128 * 128;
#pragma unroll
        for (int it = 0; it < 8; ++it) {
            int p = it * 256 + tid;
            int row = p >> 4, cpos = p & 15;
            int csrc = cpos ^ (row & 15);
            __builtin_amdgcn_global_load_lds(
                (const __attribute__((address_space(1))) void*)(Bg + row * 128 + csrc * 8),
                (__attribute__((address_space(3))) void*)(&sB[row * 128 + cpos * 8]), 16, 0, 0);
        }
    }
    __builtin_amdgcn_s_waitcnt(0);
    __syncthreads();

    const int lane = tid & 63;
    const int wid = tid >> 6;
    const int wm = wid & 1, wn = wid >> 1;   // 2x2 wave quadrants of 64x64
    const int mrow = lane & 15;
    const int g = lane >> 4;

    for (int kk = 0; kk < 3; ++kk) {
        f32x4 acc[4][4] = {};
#pragma unroll
        for (int kb = 0; kb < 4; ++kb) {
            half8 af[4], bf[4];
#pragma unroll
            for (int t = 0; t < 4; ++t) {
                int cpos8 = ((kb * 4 + g) ^ mrow) * 8;
                int ra = wm * 64 + t * 16 + mrow;
                af[t] = *reinterpret_cast<const half8*>(&sA[ra * 128 + cpos8]);
                int rb = wn * 64 + t * 16 + mrow;
                bf[t] = *reinterpret_cast<const half8*>(&sB[rb * 128 + cpos8]);
            }
#pragma unroll
            for (int mt = 0; mt < 4; ++mt)
#pragma unroll
                for (int nt = 0; nt < 4; ++nt)
                    acc[mt][nt] = __builtin_amdgcn_mfma_f32_16x16x32_f16(
                        af[mt], bf[nt], acc[mt][nt], 0, 0, 0);
        }
        __syncthreads();                 // all waves done reading sB
        if (kk < 2) {                    // stage next B, overlapped with epilogue
            const ushort* Bg = (const ushort*)Wh + (size_t)(kc0 + kk + 1) * 128 * 128;
#pragma unroll
            for (int it = 0; it < 8; ++it) {
                int p = it * 256 + tid;
                int row = p >> 4, cpos = p & 15;
                int csrc = cpos ^ (row & 15);
                __builtin_amdgcn_global_load_lds(
                    (const __attribute__((address_space(1))) void*)(Bg + row * 128 + csrc * 8),
                    (__attribute__((address_space(3))) void*)(&sB[row * 128 + cpos * 8]), 16, 0, 0);
            }
        }
        // Epilogue: lane packs acc[mt][0..3][r] (one row, 4 cols) into 8B.
        // Row-block position o' = wn*64 + mrow*4 + nt.
        _Float16* Yt = Y + (size_t)m0 * ldY + (kc0 + kk) * 128 + wn * 64 + mrow * 4;
#pragma unroll
        for (int mt = 0; mt < 4; ++mt) {
#pragma unroll
            for (int r = 0; r < 4; ++r) {
                int row = wm * 64 + mt * 16 + g * 4 + r;
                half4v hv;
#pragma unroll
                for (int nt = 0; nt < 4; ++nt) hv[nt] = (_Float16)acc[mt][nt][r];
                *reinterpret_cast<half4v*>(Yt + (size_t)row * ldY) = hv;
            }
        }
        if (kk < 2) {
            __builtin_amdgcn_s_waitcnt(0);
            __syncthreads();
        }
    }
}

// ---------------- bucket fill: counts[i]++, bucket[i][pos] = Y-offset -------
__global__ __launch_bounds__(256) void fill_buckets(
    const int* __restrict__ ih, const int* __restrict__ jl, const int* __restrict__ kc,
    int* __restrict__ counts, int* __restrict__ bucket,
    int* __restrict__ ovf_cnt, int* __restrict__ ovf_list,
    int E, int ldY) {
    int e = blockIdx.x * blockDim.x + threadIdx.x;
    if (e >= E) return;
    int i = ih[e];
    int off = jl[e] * ldY + kc[e] * 128;   // halfword offset into Y
    int pos = atomicAdd(&counts[i], 1);
    if (pos < CAP) {
        bucket[(size_t)i * CAP + pos] = off;
    } else {
        int o = atomicAdd(ovf_cnt, 1);
        if (o < OVF_MAX) { ovf_list[2 * o] = i; ovf_list[2 * o + 1] = off; }
    }
}

// ---------------- gather: out[i] = bias + sum_{e in bucket[i]} Y[off_e] -----
// 4 points per wave, 16 lanes x half8 per row: each load inst fetches 1KB.
// Invalid slots read the zeroed row at zoff.
__global__ __launch_bounds__(256) void gather_out(
    const _Float16* __restrict__ Y, const int* __restrict__ counts,
    const int* __restrict__ bucket, const float* __restrict__ biasPerm,
    float* __restrict__ out, int Nhigh, int zoff) {
    int wave = (blockIdx.x * blockDim.x + threadIdx.x) >> 6;
    int lane = threadIdx.x & 63;
    int p = lane >> 4;                  // point within wave
    int sub = lane & 15;                // 16B piece within row
    int i = wave * 4 + p;
    bool act = i < Nhigh;
    int iC = act ? i : 0;
    int nb = counts[iC];
    if (nb > CAP) nb = CAP;
    const int* bk = bucket + (size_t)iC * CAP;
    int offsA = bk[sub];                // slots 0..15 across the quarter
    int offsB = bk[sub + 16];           // slots 16..31
    float4 b0 = reinterpret_cast<const float4*>(biasPerm)[sub * 2];
    float4 b1 = reinterpret_cast<const float4*>(biasPerm)[sub * 2 + 1];
    float acc[8] = {b0.x, b0.y, b0.z, b0.w, b1.x, b1.y, b1.z, b1.w};

    int nmax = nb;
    nmax = max(nmax, __shfl_xor(nmax, 16));
    nmax = max(nmax, __shfl_xor(nmax, 32));

    for (int e0 = 0; e0 < nmax; e0 += 2) {
#pragma unroll
        for (int u = 0; u < 2; ++u) {
            int e = e0 + u;                           // wave-uniform
            int off = (e < 16) ? __shfl(offsA, p * 16 + (e & 15))
                               : __shfl(offsB, p * 16 + (e & 15));
            bool valid = act && (e < nb);
            off = valid ? off : zoff;                 // zero row
            half8 h = *reinterpret_cast<const half8*>(Y + (size_t)off + sub * 8);
#pragma unroll
            for (int t = 0; t < 8; ++t) acc[t] += (float)h[t];
        }
    }
    if (act) {
        float* op = out + (size_t)i * 128;
        int obase = (sub >> 3) * 64 + (sub & 7) * 2;
#pragma unroll
        for (int t = 0; t < 8; ++t)
            op[obase + (t & 3) * 16 + (t >> 2)] = acc[t];
    }
}

// ---------------- rare overflow application (normally 0 entries) ------------
__global__ void apply_overflow(const int* __restrict__ ovf_cnt, const int* __restrict__ ovf_list,
                               const _Float16* __restrict__ Y, float* __restrict__ out) {
    int n = *ovf_cnt;
    if (n > OVF_MAX) n = OVF_MAX;
    int lane = threadIdx.x & 63;
    int w = threadIdx.x >> 6;        // 4 waves, 1 block
    int o0p = 2 * lane, o1p = 2 * lane + 1;
    int o0 = (o0p >> 6) * 64 + (o0p & 3) * 16 + ((o0p >> 2) & 15);
    int o1 = (o1p >> 6) * 64 + (o1p & 3) * 16 + ((o1p >> 2) & 15);
    for (int o = w; o < n; o += 4) {
        int i = ovf_list[2 * o], off = ovf_list[2 * o + 1];
        half2v h = *reinterpret_cast<const half2v*>(Y + (size_t)off + lane * 2);
        float* dst = out + (size_t)i * 128;
        unsafeAtomicAdd(dst + o0, (float)h[0]);
        unsafeAtomicAdd(dst + o1, (float)h[1]);
    }
}

// ---------------- tier-3 fallback: direct per-edge matvec -------------------
__global__ void fallback_edge(const float* __restrict__ x, const float* __restrict__ w,
                              const int* __restrict__ ih, const int* __restrict__ jl,
                              const int* __restrict__ kc, float* __restrict__ out, int E) {
    int e = blockIdx.x;
    if (e >= E) return;
    int lane = threadIdx.x;   // 64 threads
    int i = ih[e], j = jl[e], k = kc[e];
    const float* xr = x + (size_t)j * 128;
    const float* wk = w + (size_t)k * 128 * 128;
    float s0 = 0.f, s1 = 0.f;
    for (int c = 0; c < 128; ++c) {
        float xv = xr[c];
        s0 += wk[(size_t)lane * 128 + c] * xv;
        s1 += wk[(size_t)(lane + 64) * 128 + c] * xv;
    }
    unsafeAtomicAdd(&out[(size_t)i * 128 + lane], s0);
    unsafeAtomicAdd(&out[(size_t)i * 128 + 64 + lane], s1);
}

extern "C" void kernel_launch(void* const* d_in, const int* in_sizes, int n_in,
                              void* d_out, int out_size, void* d_ws, size_t ws_size,
                              hipStream_t stream) {
    const float* x    = (const float*)d_in[0];
    const float* w    = (const float*)d_in[1];
    const float* bias = (const float*)d_in[2];
    const int*   ih   = (const int*)d_in[3];
    const int*   jl   = (const int*)d_in[4];
    const int*   kc   = (const int*)d_in[5];
    float* out = (float*)d_out;

    const int C = 128;
    const int Nlow = in_sizes[0] / C;
    const int K = in_sizes[1] / (C * C);
    const int E = in_sizes[3];
    const int ldY = K * C;
    const int Nhigh = out_size / C;

    const int mtiles = (Nlow + 127) / 128;
    const int Mpad = mtiles * 128;

    // ---- workspace layout -------------------------------------------------
    size_t off = 0;
    auto alloc = [&](size_t bytes) { size_t o = off; off = (off + bytes + 255) & ~(size_t)255; return o; };
    size_t xh_off   = alloc((size_t)Mpad * C * 2);
    size_t wh_off   = alloc((size_t)K * C * C * 2);
    size_t bp_off   = alloc((size_t)C * 4);                  // permuted bias
    size_t cnt_off  = alloc(((size_t)Nhigh + 1) * 4);        // counts + ovf counter
    size_t ovl_off  = alloc((size_t)OVF_MAX * 2 * 4);
    size_t bkt_off  = alloc((size_t)Nhigh * CAP * 4);
    size_t y_off    = alloc(((size_t)Mpad * ldY + C) * 2);   // + zero row
    size_t need_sort = off;

    _Float16* Xh = (_Float16*)((char*)d_ws + xh_off);
    _Float16* Wh = (_Float16*)((char*)d_ws + wh_off);
    float* biasPerm = (float*)((char*)d_ws + bp_off);
    int* counts  = (int*)((char*)d_ws + cnt_off);
    int* ovf_cnt = counts + Nhigh;
    int* ovf_lst = (int*)((char*)d_ws + ovl_off);
    int* bucket  = (int*)((char*)d_ws + bkt_off);
    _Float16* Y  = (_Float16*)((char*)d_ws + y_off);
    const int zoff = Mpad * ldY;                             // zero-row offset (halfwords)

    if (ws_size >= need_sort && (K % 3) == 0) {
        int xv4 = Nlow * C / 4, xt4 = Mpad * C / 4;
        int w4 = K * C * C / 4;
        cvt_inputs<<<(xt4 + w4 + 32 + 255) / 256, 256, 0, stream>>>(
            x, w, bias, Xh, Wh, biasPerm, xv4, xt4, w4);
        zero_ints<<<(Nhigh + 1 + 255) / 256, 256, 0, stream>>>(counts, Nhigh + 1);
        zero_ints<<<1, 64, 0, stream>>>((int*)(Y + (size_t)zoff), C / 2);
        gemm_xw<<<dim3(mtiles, K / 3), 256, 0, stream>>>(Xh, Wh, Y, ldY);
        fill_buckets<<<(E + 255) / 256, 256, 0, stream>>>(
            ih, jl, kc, counts, bucket, ovf_cnt, ovf_lst, E, ldY);
        gather_out<<<(Nhigh + 15) / 16, 256, 0, stream>>>(
            Y, counts, bucket, biasPerm, out, Nhigh, zoff);
        apply_overflow<<<1, 256, 0, stream>>>(ovf_cnt, ovf_lst, Y, out);
    } else {
        int n4out = out_size / 4;
        init_bias<<<(n4out + 255) / 256, 256, 0, stream>>>(out, bias, n4out);
        fallback_edge<<<E, 64, 0, stream>>>(x, w, ih, jl, kc, out, E);
    }
}

// Round 5
// 389.177 us; speedup vs baseline: 2.7160x; 1.0218x over previous
//
#include <hip/hip_runtime.h>

typedef _Float16 half8 __attribute__((ext_vector_type(8)));
typedef _Float16 half4v __attribute__((ext_vector_type(4)));
typedef _Float16 half2v __attribute__((ext_vector_type(2)));
typedef float f32x4 __attribute__((ext_vector_type(4)));

#define CAP 32          // bucket capacity per output point (mean load = 5)
#define OVF_MAX 4096

// Y row-block internal permutation: position o' holds output channel
//   o = (o'>>6)*64 + (o'&3)*16 + ((o'>>2)&15)
// chosen so the GEMM epilogue can write 8B-contiguous pieces per lane.

// ---------------- fp32 -> fp16 conversion of X (padded), W, bias-perm -------
__global__ void cvt_inputs(const float* __restrict__ x, const float* __restrict__ w,
                           const float* __restrict__ bias,
                           _Float16* __restrict__ Xh, _Float16* __restrict__ Wh,
                           float* __restrict__ biasPerm,
                           int xv4, int xt4, int w4) {
    int i = blockIdx.x * blockDim.x + threadIdx.x;
    if (i < xt4) {
        float4 v = (i < xv4) ? reinterpret_cast<const float4*>(x)[i]
                             : make_float4(0.f, 0.f, 0.f, 0.f);
        half4v h; h[0]=(_Float16)v.x; h[1]=(_Float16)v.y; h[2]=(_Float16)v.z; h[3]=(_Float16)v.w;
        reinterpret_cast<half4v*>(Xh)[i] = h;
    } else if (i < xt4 + w4) {
        int j = i - xt4;
        float4 v = reinterpret_cast<const float4*>(w)[j];
        half4v h; h[0]=(_Float16)v.x; h[1]=(_Float16)v.y; h[2]=(_Float16)v.z; h[3]=(_Float16)v.w;
        reinterpret_cast<half4v*>(Wh)[j] = h;
    } else if (i < xt4 + w4 + 32) {
        int j2 = i - xt4 - w4;           // float4 index into biasPerm (o'=4*j2)
        int wn = j2 >> 4, mrow = j2 & 15;
        float4 v;
        v.x = bias[wn * 64 + 0 * 16 + mrow];
        v.y = bias[wn * 64 + 1 * 16 + mrow];
        v.z = bias[wn * 64 + 2 * 16 + mrow];
        v.w = bias[wn * 64 + 3 * 16 + mrow];
        reinterpret_cast<float4*>(biasPerm)[j2] = v;
    }
}

// ---------------- zero ints (counters + bitmap / Y zero-row) ----------------
__global__ void zero_ints(int* __restrict__ p, int n) {
    int i = blockIdx.x * blockDim.x + threadIdx.x;
    if (i < n) p[i] = 0;
}

// ---------------- out[i][o] = bias[o] (fallback path only) ------------------
__global__ void init_bias(float* __restrict__ out, const float* __restrict__ bias, int n4) {
    int i = blockIdx.x * blockDim.x + threadIdx.x;
    if (i >= n4) return;
    reinterpret_cast<float4*>(out)[i] = reinterpret_cast<const float4*>(bias)[i & 31];
}

// ---------------- bucket fill + used-cell bitmap ----------------------------
__global__ __launch_bounds__(256) void fill_buckets(
    const int* __restrict__ ih, const int* __restrict__ jl, const int* __restrict__ kc,
    int* __restrict__ counts, int* __restrict__ bucket,
    int* __restrict__ ovf_cnt, int* __restrict__ ovf_list,
    unsigned* __restrict__ mask, int Mpad,
    int E, int ldY) {
    int e = blockIdx.x * blockDim.x + threadIdx.x;
    if (e >= E) return;
    int i = ih[e];
    int j = jl[e], kk = kc[e];
    int cell = kk * Mpad + j;
    atomicOr(&mask[cell >> 5], 1u << (cell & 31));
    int off = j * ldY + kk * 128;          // halfword offset into Y
    int pos = atomicAdd(&counts[i], 1);
    if (pos < CAP) {
        bucket[(size_t)i * CAP + pos] = off;
    } else {
        int o = atomicAdd(ovf_cnt, 1);
        if (o < OVF_MAX) { ovf_list[2 * o] = i; ovf_list[2 * o + 1] = off; }
    }
}

// ---------------- GEMM: Y[m, kcell-block] = X[m,:] * W[kcell]^T -------------
// A-tile staged once per block; 3 kernel cells per block; epilogue stores only
// rows whose (m,kcell) bit is set in the used-cell bitmap.
__global__ __launch_bounds__(256) void gemm_xw(
    const _Float16* __restrict__ Xh,   // [Mpad][128]
    const _Float16* __restrict__ Wh,   // [K][128][128]  (o-major, c contiguous)
    _Float16* __restrict__ Y,          // [Mpad][K*128]  (permuted row-blocks)
    const unsigned* __restrict__ mask, // used-cell bitmap, bit = kcell*Mpad+m
    int Mpad, int ldY) {
    __shared__ ushort sA[128 * 128];
    __shared__ ushort sB[128 * 128];
    const int tid = threadIdx.x;
    const int m0 = blockIdx.x * 128;
    const int kc0 = blockIdx.y * 3;
    const ushort* Ag = (const ushort*)Xh + (size_t)m0 * 128;

#pragma unroll
    for (int it = 0; it < 8; ++it) {
        int p = it * 256 + tid;
        int row = p >> 4, cpos = p & 15;
        int csrc = cpos ^ (row & 15);   // XOR swizzle keeps ds_read_b128 conflict-free
        __builtin_amdgcn_global_load_lds(
            (const __attribute__((address_space(1))) void*)(Ag + row * 128 + csrc * 8),
            (__attribute__((address_space(3))) void*)(&sA[row * 128 + cpos * 8]), 16, 0, 0);
    }
    {   // stage B for kcell kc0
        const ushort* Bg = (const ushort*)Wh + (size_t)kc0 * 128 * 128;
#pragma unroll
        for (int it = 0; it < 8; ++it) {
            int p = it * 256 + tid;
            int row = p >> 4, cpos = p & 15;
            int csrc = cpos ^ (row & 15);
            __builtin_amdgcn_global_load_lds(
                (const __attribute__((address_space(1))) void*)(Bg + row * 128 + csrc * 8),
                (__attribute__((address_space(3))) void*)(&sB[row * 128 + cpos * 8]), 16, 0, 0);
        }
    }
    __builtin_amdgcn_s_waitcnt(0);
    __syncthreads();

    const int lane = tid & 63;
    const int wid = tid >> 6;
    const int wm = wid & 1, wn = wid >> 1;   // 2x2 wave quadrants of 64x64
    const int mrow = lane & 15;
    const int g = lane >> 4;

    for (int kk = 0; kk < 3; ++kk) {
        f32x4 acc[4][4] = {};
#pragma unroll
        for (int kb = 0; kb < 4; ++kb) {
            half8 af[4], bf[4];
#pragma unroll
            for (int t = 0; t < 4; ++t) {
                int cpos8 = ((kb * 4 + g) ^ mrow) * 8;
                int ra = wm * 64 + t * 16 + mrow;
                af[t] = *reinterpret_cast<const half8*>(&sA[ra * 128 + cpos8]);
                int rb = wn * 64 + t * 16 + mrow;
                bf[t] = *reinterpret_cast<const half8*>(&sB[rb * 128 + cpos8]);
            }
#pragma unroll
            for (int mt = 0; mt < 4; ++mt)
#pragma unroll
                for (int nt = 0; nt < 4; ++nt)
                    acc[mt][nt] = __builtin_amdgcn_mfma_f32_16x16x32_f16(
                        af[mt], bf[nt], acc[mt][nt], 0, 0, 0);
        }
        __syncthreads();                 // all waves done reading sB
        if (kk < 2) {                    // stage next B, overlapped with epilogue
            const ushort* Bg = (const ushort*)Wh + (size_t)(kc0 + kk + 1) * 128 * 128;
#pragma unroll
            for (int it = 0; it < 8; ++it) {
                int p = it * 256 + tid;
                int row = p >> 4, cpos = p & 15;
                int csrc = cpos ^ (row & 15);
                __builtin_amdgcn_global_load_lds(
                    (const __attribute__((address_space(1))) void*)(Bg + row * 128 + csrc * 8),
                    (__attribute__((address_space(3))) void*)(&sB[row * 128 + cpos * 8]), 16, 0, 0);
            }
        }
        // Mask dwords for this (kcell, 128-row block): 4 uniform dwords.
        const unsigned* mwp = mask + (((size_t)(kc0 + kk) * Mpad + m0) >> 5);
        unsigned mw0 = mwp[0], mw1 = mwp[1], mw2 = mwp[2], mw3 = mwp[3];
        unsigned mAsel = wm ? mw2 : mw0;   // rows wm*64 + 0..31  (mt 0,1)
        unsigned mBsel = wm ? mw3 : mw1;   // rows wm*64 + 32..63 (mt 2,3)
        // Epilogue: lane packs acc[mt][0..3][r] (one row, 4 cols) into 8B.
        // Row-block position o' = wn*64 + mrow*4 + nt.
        _Float16* Yt = Y + (size_t)m0 * ldY + (kc0 + kk) * 128 + wn * 64 + mrow * 4;
#pragma unroll
        for (int mt = 0; mt < 4; ++mt) {
            unsigned msel = (mt < 2) ? mAsel : mBsel;
#pragma unroll
            for (int r = 0; r < 4; ++r) {
                int bit = (mt & 1) * 16 + g * 4 + r;
                if ((msel >> bit) & 1u) {
                    int row = wm * 64 + mt * 16 + g * 4 + r;
                    half4v hv;
#pragma unroll
                    for (int nt = 0; nt < 4; ++nt) hv[nt] = (_Float16)acc[mt][nt][r];
                    *reinterpret_cast<half4v*>(Yt + (size_t)row * ldY) = hv;
                }
            }
        }
        if (kk < 2) {
            __builtin_amdgcn_s_waitcnt(0);
            __syncthreads();
        }
    }
}

// ---------------- gather: out[i] = bias + sum_{e in bucket[i]} Y[off_e] -----
// 4 points per wave, 16 lanes x half8 per row; unroll-4 for loads in flight.
__global__ __launch_bounds__(256) void gather_out(
    const _Float16* __restrict__ Y, const int* __restrict__ counts,
    const int* __restrict__ bucket, const float* __restrict__ biasPerm,
    float* __restrict__ out, int Nhigh, int zoff) {
    int wave = (blockIdx.x * blockDim.x + threadIdx.x) >> 6;
    int lane = threadIdx.x & 63;
    int p = lane >> 4;                  // point within wave
    int sub = lane & 15;                // 16B piece within row
    int i = wave * 4 + p;
    bool act = i < Nhigh;
    int iC = act ? i : 0;
    int nb = counts[iC];
    if (nb > CAP) nb = CAP;
    const int* bk = bucket + (size_t)iC * CAP;
    int offsA = bk[sub];                // slots 0..15 across the quarter
    int offsB = bk[sub + 16];           // slots 16..31
    float4 b0 = reinterpret_cast<const float4*>(biasPerm)[sub * 2];
    float4 b1 = reinterpret_cast<const float4*>(biasPerm)[sub * 2 + 1];
    float acc[8] = {b0.x, b0.y, b0.z, b0.w, b1.x, b1.y, b1.z, b1.w};

    int nmax = nb;
    nmax = max(nmax, __shfl_xor(nmax, 16));
    nmax = max(nmax, __shfl_xor(nmax, 32));

    for (int e0 = 0; e0 < nmax; e0 += 4) {
#pragma unroll
        for (int u = 0; u < 4; ++u) {
            int e = e0 + u;                           // wave-uniform
            int off = (e < 16) ? __shfl(offsA, p * 16 + (e & 15))
                               : __shfl(offsB, p * 16 + (e & 15));
            bool valid = act && (e < nb);
            off = valid ? off : zoff;                 // zero row
            half8 h = *reinterpret_cast<const half8*>(Y + (size_t)off + sub * 8);
#pragma unroll
            for (int t = 0; t < 8; ++t) acc[t] += (float)h[t];
        }
    }
    if (act) {
        float* op = out + (size_t)i * 128;
        int obase = (sub >> 3) * 64 + (sub & 7) * 2;
#pragma unroll
        for (int t = 0; t < 8; ++t)
            op[obase + (t & 3) * 16 + (t >> 2)] = acc[t];
    }
}

// ---------------- rare overflow application (normally 0 entries) ------------
__global__ void apply_overflow(const int* __restrict__ ovf_cnt, const int* __restrict__ ovf_list,
                               const _Float16* __restrict__ Y, float* __restrict__ out) {
    int n = *ovf_cnt;
    if (n > OVF_MAX) n = OVF_MAX;
    int lane = threadIdx.x & 63;
    int w = threadIdx.x >> 6;        // 4 waves, 1 block
    int o0p = 2 * lane, o1p = 2 * lane + 1;
    int o0 = (o0p >> 6) * 64 + (o0p & 3) * 16 + ((o0p >> 2) & 15);
    int o1 = (o1p >> 6) * 64 + (o1p & 3) * 16 + ((o1p >> 2) & 15);
    for (int o = w; o < n; o += 4) {
        int i = ovf_list[2 * o], off = ovf_list[2 * o + 1];
        half2v h = *reinterpret_cast<const half2v*>(Y + (size_t)off + lane * 2);
        float* dst = out + (size_t)i * 128;
        unsafeAtomicAdd(dst + o0, (float)h[0]);
        unsafeAtomicAdd(dst + o1, (float)h[1]);
    }
}

// ---------------- tier-3 fallback: direct per-edge matvec -------------------
__global__ void fallback_edge(const float* __restrict__ x, const float* __restrict__ w,
                              const int* __restrict__ ih, const int* __restrict__ jl,
                              const int* __restrict__ kc, float* __restrict__ out, int E) {
    int e = blockIdx.x;
    if (e >= E) return;
    int lane = threadIdx.x;   // 64 threads
    int i = ih[e], j = jl[e], k = kc[e];
    const float* xr = x + (size_t)j * 128;
    const float* wk = w + (size_t)k * 128 * 128;
    float s0 = 0.f, s1 = 0.f;
    for (int c = 0; c < 128; ++c) {
        float xv = xr[c];
        s0 += wk[(size_t)lane * 128 + c] * xv;
        s1 += wk[(size_t)(lane + 64) * 128 + c] * xv;
    }
    unsafeAtomicAdd(&out[(size_t)i * 128 + lane], s0);
    unsafeAtomicAdd(&out[(size_t)i * 128 + 64 + lane], s1);
}

extern "C" void kernel_launch(void* const* d_in, const int* in_sizes, int n_in,
                              void* d_out, int out_size, void* d_ws, size_t ws_size,
                              hipStream_t stream) {
    const float* x    = (const float*)d_in[0];
    const float* w    = (const float*)d_in[1];
    const float* bias = (const float*)d_in[2];
    const int*   ih   = (const int*)d_in[3];
    const int*   jl   = (const int*)d_in[4];
    const int*   kc   = (const int*)d_in[5];
    float* out = (float*)d_out;

    const int C = 128;
    const int Nlow = in_sizes[0] / C;
    const int K = in_sizes[1] / (C * C);
    const int E = in_sizes[3];
    const int ldY = K * C;
    const int Nhigh = out_size / C;

    const int mtiles = (Nlow + 127) / 128;
    const int Mpad = mtiles * 128;
    const int maskwords = (Mpad * K + 31) / 32;

    // ---- workspace layout -------------------------------------------------
    size_t off = 0;
    auto alloc = [&](size_t bytes) { size_t o = off; off = (off + bytes + 255) & ~(size_t)255; return o; };
    size_t xh_off   = alloc((size_t)Mpad * C * 2);
    size_t wh_off   = alloc((size_t)K * C * C * 2);
    size_t bp_off   = alloc((size_t)C * 4);                  // permuted bias
    size_t cnt_off  = alloc(((size_t)Nhigh + 1 + maskwords) * 4); // counts+ovf+mask
    size_t ovl_off  = alloc((size_t)OVF_MAX * 2 * 4);
    size_t bkt_off  = alloc((size_t)Nhigh * CAP * 4);
    size_t y_off    = alloc(((size_t)Mpad * ldY + C) * 2);   // + zero row
    size_t need_sort = off;

    _Float16* Xh = (_Float16*)((char*)d_ws + xh_off);
    _Float16* Wh = (_Float16*)((char*)d_ws + wh_off);
    float* biasPerm = (float*)((char*)d_ws + bp_off);
    int* counts  = (int*)((char*)d_ws + cnt_off);
    int* ovf_cnt = counts + Nhigh;
    unsigned* mask = (unsigned*)(counts + Nhigh + 1);
    int* ovf_lst = (int*)((char*)d_ws + ovl_off);
    int* bucket  = (int*)((char*)d_ws + bkt_off);
    _Float16* Y  = (_Float16*)((char*)d_ws + y_off);
    const int zoff = Mpad * ldY;                             // zero-row offset (halfwords)

    if (ws_size >= need_sort && (K % 3) == 0) {
        int xv4 = Nlow * C / 4, xt4 = Mpad * C / 4;
        int w4 = K * C * C / 4;
        cvt_inputs<<<(xt4 + w4 + 32 + 255) / 256, 256, 0, stream>>>(
            x, w, bias, Xh, Wh, biasPerm, xv4, xt4, w4);
        int nz = Nhigh + 1 + maskwords;
        zero_ints<<<(nz + 255) / 256, 256, 0, stream>>>(counts, nz);
        zero_ints<<<1, 64, 0, stream>>>((int*)(Y + (size_t)zoff), C / 2);
        fill_buckets<<<(E + 255) / 256, 256, 0, stream>>>(
            ih, jl, kc, counts, bucket, ovf_cnt, ovf_lst, mask, Mpad, E, ldY);
        gemm_xw<<<dim3(mtiles, K / 3), 256, 0, stream>>>(Xh, Wh, Y, mask, Mpad, ldY);
        gather_out<<<(Nhigh + 15) / 16, 256, 0, stream>>>(
            Y, counts, bucket, biasPerm, out, Nhigh, zoff);
        apply_overflow<<<1, 256, 0, stream>>>(ovf_cnt, ovf_lst, Y, out);
    } else {
        int n4out = out_size / 4;
        init_bias<<<(n4out + 255) / 256, 256, 0, stream>>>(out, bias, n4out);
        fallback_edge<<<E, 64, 0, stream>>>(x, w, ih, jl, kc, out, E);
    }
}